// Round 1
// baseline (2555.811 us; speedup 1.0000x reference)
//
#include <hip/hip_runtime.h>
#include <hip/hip_bf16.h>

#define NN 100000
#define EE 3200000
#define FIN 512
#define HH 256
#define CC 64
#define KSTEPS 10

typedef __attribute__((ext_vector_type(8))) short bf16x8;
typedef __attribute__((ext_vector_type(4))) float f32x4;

__device__ __forceinline__ short f2bf(float f) {
    union { __hip_bfloat16 h; short s; } u;
    u.h = __float2bfloat16(f);
    return u.s;
}

// ---------------- weight prep: transpose + bf16 ----------------
__global__ void prep_w(const float* __restrict__ w0, const float* __restrict__ w1,
                       short* __restrict__ w0t, short* __restrict__ w1t) {
    int t = blockIdx.x * blockDim.x + threadIdx.x;
    if (t < FIN * HH) {                   // w0 [512][256] -> w0t [256][512]
        int k = t >> 8, n = t & 255;
        w0t[n * FIN + k] = f2bf(w0[t]);
    } else if (t < FIN * HH + HH * CC) {  // w1 [256][64] -> w1t [64][256]
        int u = t - FIN * HH;
        int k = u >> 6, n = u & 63;
        w1t[n * HH + k] = f2bf(w1[u]);
    }
}

// ---------------- CSR build ----------------
__global__ void hist_kernel(const int* __restrict__ ei, int* __restrict__ cnt) {
    int t = blockIdx.x * blockDim.x + threadIdx.x;
    if (t < EE) {
        unsigned d = (unsigned)ei[EE + t];
        if (d < NN) atomicAdd(&cnt[d], 1);
    }
}

__global__ void scan_kernel(const int* __restrict__ cnt, int* __restrict__ rp,
                            float* __restrict__ dinv) {
    __shared__ int part[1024];
    int t = threadIdx.x;
    const int chunk = (NN + 1023) / 1024;  // 98
    int lo = t * chunk, hi = min(lo + chunk, NN);
    int s = 0;
    for (int i = lo; i < hi; ++i) s += cnt[i] + 1;
    part[t] = s;
    __syncthreads();
    for (int off = 1; off < 1024; off <<= 1) {
        int add = (t >= off) ? part[t - off] : 0;
        __syncthreads();
        part[t] += add;
        __syncthreads();
    }
    int excl = (t == 0) ? 0 : part[t - 1];
    for (int i = lo; i < hi; ++i) {
        rp[i] = excl;
        int deg = cnt[i] + 1;
        excl += deg;
        dinv[i] = rsqrtf((float)deg);
    }
    if (t == 1023) rp[NN] = excl;
}

__global__ void fill_kernel(const int* __restrict__ ei, const int* __restrict__ rp,
                            int* __restrict__ fc, const float* __restrict__ dinv,
                            int2* __restrict__ ed) {
    int t = blockIdx.x * blockDim.x + threadIdx.x;
    if (t < EE) {
        unsigned s = (unsigned)ei[t];
        unsigned d = (unsigned)ei[EE + t];
        if (s < NN && d < NN) {
            int pos = rp[d] + atomicAdd(&fc[d], 1);
            ed[pos] = make_int2((int)s, __float_as_int(dinv[s] * dinv[d]));
        }
    } else if (t < EE + NN) {
        int i = t - EE;
        float v = dinv[i];
        ed[rp[i + 1] - 1] = make_int2(i, __float_as_int(v * v));
    }
}

// ---------------- GEMM1: h0 = relu(x @ w0 + b0), bf16 out [100096][256] ----------------
__global__ __launch_bounds__(256) void gemm1(const float* __restrict__ x,
                                             const short* __restrict__ w0t,
                                             const float* __restrict__ b0,
                                             short* __restrict__ h0) {
    __shared__ __align__(16) short As[128 * 40];
    __shared__ __align__(16) short Bs[128 * 40];
    int tid = threadIdx.x;
    int row0 = blockIdx.x * 128, n0 = blockIdx.y * 128;
    int lane = tid & 63, wid = tid >> 6;
    int wm = wid >> 1, wn = wid & 1;  // 2x2 waves, 64x64 each
    f32x4 acc[4][4] = {};

    for (int kt = 0; kt < FIN; kt += 32) {
        // stage A: 128 rows x 32 k, fp32 -> bf16
#pragma unroll
        for (int i = 0; i < 4; ++i) {
            int id = i * 256 + tid;        // 0..1023
            int r = id >> 3, kg = id & 7;  // row, k-group of 4
            int grow = row0 + r;
            float4 v = make_float4(0.f, 0.f, 0.f, 0.f);
            if (grow < NN) v = *(const float4*)(x + (size_t)grow * FIN + kt + kg * 4);
            short4 b;
            b.x = f2bf(v.x); b.y = f2bf(v.y); b.z = f2bf(v.z); b.w = f2bf(v.w);
            *(short4*)(&As[r * 40 + kg * 4]) = b;
        }
        // stage B: 128 cols x 32 k from w0t (bf16, contiguous in k)
#pragma unroll
        for (int i = 0; i < 2; ++i) {
            int id = i * 256 + tid;        // 0..511
            int n = id >> 2, kc = id & 3;  // col, k-chunk of 8
            int4 v = *(const int4*)(w0t + (size_t)(n0 + n) * FIN + kt + kc * 8);
            *(int4*)(&Bs[n * 40 + kc * 8]) = v;
        }
        __syncthreads();
        bf16x8 af[4], bfr[4];
#pragma unroll
        for (int i = 0; i < 4; ++i)
            af[i] = *(const bf16x8*)(&As[(wm * 64 + i * 16 + (lane & 15)) * 40 + (lane >> 4) * 8]);
#pragma unroll
        for (int j = 0; j < 4; ++j)
            bfr[j] = *(const bf16x8*)(&Bs[(wn * 64 + j * 16 + (lane & 15)) * 40 + (lane >> 4) * 8]);
#pragma unroll
        for (int i = 0; i < 4; ++i)
#pragma unroll
            for (int j = 0; j < 4; ++j)
                acc[i][j] = __builtin_amdgcn_mfma_f32_16x16x32_bf16(af[i], bfr[j], acc[i][j], 0, 0, 0);
        __syncthreads();
    }
    // epilogue: +b0, relu, bf16 store (rows padded to 100096, store unconditional)
#pragma unroll
    for (int i = 0; i < 4; ++i)
#pragma unroll
        for (int j = 0; j < 4; ++j) {
            int gcol = n0 + wn * 64 + j * 16 + (lane & 15);
            float bias = b0[gcol];
#pragma unroll
            for (int q = 0; q < 4; ++q) {
                int grow = row0 + wm * 64 + i * 16 + (lane >> 4) * 4 + q;
                float v = acc[i][j][q] + bias;
                if (v < 0.f) v = 0.f;
                h0[(size_t)grow * HH + gcol] = f2bf(v);
            }
        }
}

// ---------------- GEMM2: h = h0 @ w1 + b1, f32 out [100000][64] ----------------
__global__ __launch_bounds__(256) void gemm2(const short* __restrict__ h0,
                                             const short* __restrict__ w1t,
                                             const float* __restrict__ b1,
                                             float* __restrict__ h) {
    __shared__ __align__(16) short As[128 * 40];
    __shared__ __align__(16) short Bs[64 * 40];
    int tid = threadIdx.x;
    int row0 = blockIdx.x * 128;
    int lane = tid & 63, wid = tid >> 6;
    int wm = wid >> 1, wn = wid & 1;  // wave tile 64 x 32
    f32x4 acc[4][2] = {};

    for (int kt = 0; kt < HH; kt += 32) {
#pragma unroll
        for (int i = 0; i < 2; ++i) {
            int id = i * 256 + tid;        // 0..511
            int r = id >> 2, kc = id & 3;
            int4 v = *(const int4*)(h0 + (size_t)(row0 + r) * HH + kt + kc * 8);
            *(int4*)(&As[r * 40 + kc * 8]) = v;
        }
        {
            int n = tid >> 2, kc = tid & 3;  // 64 x 4 chunks = 256 threads
            int4 v = *(const int4*)(w1t + (size_t)n * HH + kt + kc * 8);
            *(int4*)(&Bs[n * 40 + kc * 8]) = v;
        }
        __syncthreads();
        bf16x8 af[4], bfr[2];
#pragma unroll
        for (int i = 0; i < 4; ++i)
            af[i] = *(const bf16x8*)(&As[(wm * 64 + i * 16 + (lane & 15)) * 40 + (lane >> 4) * 8]);
#pragma unroll
        for (int j = 0; j < 2; ++j)
            bfr[j] = *(const bf16x8*)(&Bs[(wn * 32 + j * 16 + (lane & 15)) * 40 + (lane >> 4) * 8]);
#pragma unroll
        for (int i = 0; i < 4; ++i)
#pragma unroll
            for (int j = 0; j < 2; ++j)
                acc[i][j] = __builtin_amdgcn_mfma_f32_16x16x32_bf16(af[i], bfr[j], acc[i][j], 0, 0, 0);
        __syncthreads();
    }
#pragma unroll
    for (int i = 0; i < 4; ++i)
#pragma unroll
        for (int j = 0; j < 2; ++j) {
            int col = wn * 32 + j * 16 + (lane & 15);
            float bias = b1[col];
#pragma unroll
            for (int q = 0; q < 4; ++q) {
                int grow = row0 + wm * 64 + i * 16 + (lane >> 4) * 4 + q;
                if (grow < NN) h[(size_t)grow * CC + col] = acc[i][j][q] + bias;
            }
        }
}

// ---------------- propagation: zout = 0.9 * A_hat @ zin + 0.1 * h ----------------
__global__ __launch_bounds__(256) void prop(const float* __restrict__ zin,
                                            const float* __restrict__ h,
                                            float* __restrict__ zout,
                                            const int* __restrict__ rp,
                                            const int2* __restrict__ ed) {
    int node = blockIdx.x * 4 + (threadIdx.x >> 6);
    if (node >= NN) return;
    int lane = threadIdx.x & 63;
    int beg = rp[node], end = rp[node + 1];
    float acc0 = 0.f, acc1 = 0.f;
    int e = beg;
    for (; e + 1 < end; e += 2) {
        int2 a = ed[e];
        int2 b = ed[e + 1];
        acc0 += __int_as_float(a.y) * zin[(size_t)a.x * CC + lane];
        acc1 += __int_as_float(b.y) * zin[(size_t)b.x * CC + lane];
    }
    if (e < end) {
        int2 a = ed[e];
        acc0 += __int_as_float(a.y) * zin[(size_t)a.x * CC + lane];
    }
    zout[(size_t)node * CC + lane] = 0.9f * (acc0 + acc1) + 0.1f * h[(size_t)node * CC + lane];
}

// ---------------- log_softmax in-place over rows of 64 ----------------
__global__ __launch_bounds__(256) void lsm(float* __restrict__ z) {
    int node = blockIdx.x * 4 + (threadIdx.x >> 6);
    if (node >= NN) return;
    int lane = threadIdx.x & 63;
    float v = z[(size_t)node * CC + lane];
    float m = v;
#pragma unroll
    for (int off = 32; off > 0; off >>= 1) m = fmaxf(m, __shfl_xor(m, off));
    float e = expf(v - m);
    float s = e;
#pragma unroll
    for (int off = 32; off > 0; off >>= 1) s += __shfl_xor(s, off);
    z[(size_t)node * CC + lane] = v - m - logf(s);
}

extern "C" void kernel_launch(void* const* d_in, const int* in_sizes, int n_in,
                              void* d_out, int out_size, void* d_ws, size_t ws_size,
                              hipStream_t stream) {
    const float* x  = (const float*)d_in[0];
    const float* w0 = (const float*)d_in[1];
    const float* b0 = (const float*)d_in[2];
    const float* w1 = (const float*)d_in[3];
    const float* b1 = (const float*)d_in[4];
    const int*   ei = (const int*)d_in[5];

    char* ws = (char*)d_ws;
    size_t off = 0;
    auto take = [&](size_t n) { size_t r = off; off += (n + 255) & ~(size_t)255; return r; };
    size_t o_h0   = take((size_t)100096 * HH * 2);   // bf16 h0, padded rows
    size_t o_h    = take((size_t)NN * CC * 4);       // f32 h (teleport term)
    size_t o_ed   = take((size_t)(EE + NN) * 8);     // CSR edge data {src, norm}
    size_t o_rp   = take((size_t)(NN + 1) * 4);
    size_t o_cnt  = take((size_t)NN * 4);
    size_t o_fc   = take((size_t)NN * 4);
    size_t o_dinv = take((size_t)NN * 4);
    size_t o_w0t  = take((size_t)HH * FIN * 2);
    size_t o_w1t  = take((size_t)CC * HH * 2);

    short* h0   = (short*)(ws + o_h0);
    float* h    = (float*)(ws + o_h);
    int2*  ed   = (int2*)(ws + o_ed);
    int*   rp   = (int*)(ws + o_rp);
    int*   cnt  = (int*)(ws + o_cnt);
    int*   fc   = (int*)(ws + o_fc);
    float* dinv = (float*)(ws + o_dinv);
    short* w0t  = (short*)(ws + o_w0t);
    short* w1t  = (short*)(ws + o_w1t);
    float* zA   = (float*)(ws + o_h0);   // alias h0 (dead after gemm2)
    float* zB   = (float*)d_out;

    prep_w<<<(FIN * HH + HH * CC + 255) / 256, 256, 0, stream>>>(w0, w1, w0t, w1t);
    hipMemsetAsync(ws + o_cnt, 0, 2 * (((size_t)NN * 4 + 255) & ~(size_t)255), stream);
    hist_kernel<<<(EE + 255) / 256, 256, 0, stream>>>(ei, cnt);
    scan_kernel<<<1, 1024, 0, stream>>>(cnt, rp, dinv);
    fill_kernel<<<(EE + NN + 255) / 256, 256, 0, stream>>>(ei, rp, fc, dinv, ed);

    gemm1<<<dim3(782, 2), 256, 0, stream>>>(x, w0t, b0, h0);
    gemm2<<<782, 256, 0, stream>>>(h0, w1t, b1, h);

    const float* in = h;
    for (int k = 0; k < KSTEPS; ++k) {
        float* o = (k & 1) ? zB : zA;
        prop<<<(NN + 3) / 4, 256, 0, stream>>>(in, h, o, rp, ed);
        in = o;
    }
    lsm<<<(NN + 3) / 4, 256, 0, stream>>>((float*)d_out);
}

// Round 2
// 1624.768 us; speedup vs baseline: 1.5730x; 1.5730x over previous
//
#include <hip/hip_runtime.h>
#include <hip/hip_bf16.h>

#define NN 100000
#define EE 3200000
#define FIN 512
#define HH 256
#define CC 64
#define KSTEPS 10
#define SB 391   // ceil(NN/256)

typedef __attribute__((ext_vector_type(8))) short bf16x8;
typedef __attribute__((ext_vector_type(4))) float f32x4;

__device__ __forceinline__ short f2bf(float f) {
    union { __hip_bfloat16 h; short s; } u;
    u.h = __float2bfloat16(f);
    return u.s;
}

// ---------------- weight prep: transpose + bf16 ----------------
__global__ void prep_w(const float* __restrict__ w0, const float* __restrict__ w1,
                       short* __restrict__ w0t, short* __restrict__ w1t) {
    int t = blockIdx.x * blockDim.x + threadIdx.x;
    if (t < FIN * HH) {                   // w0 [512][256] -> w0t [256][512]
        int k = t >> 8, n = t & 255;
        w0t[n * FIN + k] = f2bf(w0[t]);
    } else if (t < FIN * HH + HH * CC) {  // w1 [256][64] -> w1t [64][256]
        int u = t - FIN * HH;
        int k = u >> 6, n = u & 63;
        w1t[n * HH + k] = f2bf(w1[u]);
    }
}

// ---------------- CSR build ----------------
__global__ void hist_kernel(const int* __restrict__ ei, int* __restrict__ cnt) {
    int t = blockIdx.x * blockDim.x + threadIdx.x;
    if (t < EE) {
        unsigned d = (unsigned)ei[EE + t];
        if (d < NN) atomicAdd(&cnt[d], 1);
    }
}

// deg reduce per block + dinv
__global__ __launch_bounds__(256) void deg_kernel(const int* __restrict__ cnt,
                                                  float* __restrict__ dinv,
                                                  int* __restrict__ bsum) {
    __shared__ int red[256];
    int i = blockIdx.x * 256 + threadIdx.x;
    int d = 0;
    if (i < NN) { d = cnt[i] + 1; dinv[i] = rsqrtf((float)d); }
    red[threadIdx.x] = d;
    __syncthreads();
    for (int off = 128; off > 0; off >>= 1) {
        if (threadIdx.x < off) red[threadIdx.x] += red[threadIdx.x + off];
        __syncthreads();
    }
    if (threadIdx.x == 0) bsum[blockIdx.x] = red[0];
}

// exclusive scan of 391 block sums
__global__ __launch_bounds__(512) void scanb_kernel(const int* __restrict__ bsum,
                                                    int* __restrict__ boff) {
    __shared__ int sh[512];
    int t = threadIdx.x;
    int v = (t < SB) ? bsum[t] : 0;
    sh[t] = v;
    __syncthreads();
    for (int off = 1; off < 512; off <<= 1) {
        int add = (t >= off) ? sh[t - off] : 0;
        __syncthreads();
        sh[t] += add;
        __syncthreads();
    }
    if (t < SB) boff[t] = sh[t] - v;  // exclusive
}

// per-block exclusive scan -> rp
__global__ __launch_bounds__(256) void rp_kernel(const int* __restrict__ cnt,
                                                 const int* __restrict__ boff,
                                                 int* __restrict__ rp) {
    __shared__ int sh[256];
    int i = blockIdx.x * 256 + threadIdx.x;
    int d = (i < NN) ? cnt[i] + 1 : 0;
    sh[threadIdx.x] = d;
    __syncthreads();
    for (int off = 1; off < 256; off <<= 1) {
        int add = (threadIdx.x >= off) ? sh[threadIdx.x - off] : 0;
        __syncthreads();
        sh[threadIdx.x] += add;
        __syncthreads();
    }
    int incl = sh[threadIdx.x];
    if (i < NN) rp[i] = boff[blockIdx.x] + incl - d;
    if (i == NN - 1) rp[NN] = boff[blockIdx.x] + incl;
}

__global__ void fill_kernel(const int* __restrict__ ei, const int* __restrict__ rp,
                            int* __restrict__ fc, const float* __restrict__ dinv,
                            int2* __restrict__ ed) {
    int t = blockIdx.x * blockDim.x + threadIdx.x;
    if (t < EE) {
        unsigned s = (unsigned)ei[t];
        unsigned d = (unsigned)ei[EE + t];
        if (s < NN && d < NN) {
            int pos = rp[d] + atomicAdd(&fc[d], 1);
            ed[pos] = make_int2((int)s, __float_as_int(dinv[s] * dinv[d]));
        }
    } else if (t < EE + NN) {
        int i = t - EE;
        float v = dinv[i];
        ed[rp[i + 1] - 1] = make_int2(i, __float_as_int(v * v));
    }
}

// ---------------- GEMM1: h0 = relu(x @ w0 + b0), bf16 out [100096][256] ----------------
__global__ __launch_bounds__(256) void gemm1(const float* __restrict__ x,
                                             const short* __restrict__ w0t,
                                             const float* __restrict__ b0,
                                             short* __restrict__ h0) {
    __shared__ __align__(16) short As[128 * 40];
    __shared__ __align__(16) short Bs[128 * 40];
    int tid = threadIdx.x;
    int row0 = blockIdx.x * 128, n0 = blockIdx.y * 128;
    int lane = tid & 63, wid = tid >> 6;
    int wm = wid >> 1, wn = wid & 1;  // 2x2 waves, 64x64 each
    f32x4 acc[4][4] = {};

    for (int kt = 0; kt < FIN; kt += 32) {
#pragma unroll
        for (int i = 0; i < 4; ++i) {
            int id = i * 256 + tid;
            int r = id >> 3, kg = id & 7;
            int grow = row0 + r;
            float4 v = make_float4(0.f, 0.f, 0.f, 0.f);
            if (grow < NN) v = *(const float4*)(x + (size_t)grow * FIN + kt + kg * 4);
            short4 b;
            b.x = f2bf(v.x); b.y = f2bf(v.y); b.z = f2bf(v.z); b.w = f2bf(v.w);
            *(short4*)(&As[r * 40 + kg * 4]) = b;
        }
#pragma unroll
        for (int i = 0; i < 2; ++i) {
            int id = i * 256 + tid;
            int n = id >> 2, kc = id & 3;
            int4 v = *(const int4*)(w0t + (size_t)(n0 + n) * FIN + kt + kc * 8);
            *(int4*)(&Bs[n * 40 + kc * 8]) = v;
        }
        __syncthreads();
        bf16x8 af[4], bfr[4];
#pragma unroll
        for (int i = 0; i < 4; ++i)
            af[i] = *(const bf16x8*)(&As[(wm * 64 + i * 16 + (lane & 15)) * 40 + (lane >> 4) * 8]);
#pragma unroll
        for (int j = 0; j < 4; ++j)
            bfr[j] = *(const bf16x8*)(&Bs[(wn * 64 + j * 16 + (lane & 15)) * 40 + (lane >> 4) * 8]);
#pragma unroll
        for (int i = 0; i < 4; ++i)
#pragma unroll
            for (int j = 0; j < 4; ++j)
                acc[i][j] = __builtin_amdgcn_mfma_f32_16x16x32_bf16(af[i], bfr[j], acc[i][j], 0, 0, 0);
        __syncthreads();
    }
#pragma unroll
    for (int i = 0; i < 4; ++i)
#pragma unroll
        for (int j = 0; j < 4; ++j) {
            int gcol = n0 + wn * 64 + j * 16 + (lane & 15);
            float bias = b0[gcol];
#pragma unroll
            for (int q = 0; q < 4; ++q) {
                int grow = row0 + wm * 64 + i * 16 + (lane >> 4) * 4 + q;
                float v = acc[i][j][q] + bias;
                if (v < 0.f) v = 0.f;
                h0[(size_t)grow * HH + gcol] = f2bf(v);
            }
        }
}

// ---------------- GEMM2: h = h0 @ w1 + b1, f32 out [100000][64] ----------------
__global__ __launch_bounds__(256) void gemm2(const short* __restrict__ h0,
                                             const short* __restrict__ w1t,
                                             const float* __restrict__ b1,
                                             float* __restrict__ h) {
    __shared__ __align__(16) short As[128 * 40];
    __shared__ __align__(16) short Bs[64 * 40];
    int tid = threadIdx.x;
    int row0 = blockIdx.x * 128;
    int lane = tid & 63, wid = tid >> 6;
    int wm = wid >> 1, wn = wid & 1;
    f32x4 acc[4][2] = {};

    for (int kt = 0; kt < HH; kt += 32) {
#pragma unroll
        for (int i = 0; i < 2; ++i) {
            int id = i * 256 + tid;
            int r = id >> 2, kc = id & 3;
            int4 v = *(const int4*)(h0 + (size_t)(row0 + r) * HH + kt + kc * 8);
            *(int4*)(&As[r * 40 + kc * 8]) = v;
        }
        {
            int n = tid >> 2, kc = tid & 3;
            int4 v = *(const int4*)(w1t + (size_t)n * HH + kt + kc * 8);
            *(int4*)(&Bs[n * 40 + kc * 8]) = v;
        }
        __syncthreads();
        bf16x8 af[4], bfr[2];
#pragma unroll
        for (int i = 0; i < 4; ++i)
            af[i] = *(const bf16x8*)(&As[(wm * 64 + i * 16 + (lane & 15)) * 40 + (lane >> 4) * 8]);
#pragma unroll
        for (int j = 0; j < 2; ++j)
            bfr[j] = *(const bf16x8*)(&Bs[(wn * 32 + j * 16 + (lane & 15)) * 40 + (lane >> 4) * 8]);
#pragma unroll
        for (int i = 0; i < 4; ++i)
#pragma unroll
            for (int j = 0; j < 2; ++j)
                acc[i][j] = __builtin_amdgcn_mfma_f32_16x16x32_bf16(af[i], bfr[j], acc[i][j], 0, 0, 0);
        __syncthreads();
    }
#pragma unroll
    for (int i = 0; i < 4; ++i)
#pragma unroll
        for (int j = 0; j < 2; ++j) {
            int col = wn * 32 + j * 16 + (lane & 15);
            float bias = b1[col];
#pragma unroll
            for (int q = 0; q < 4; ++q) {
                int grow = row0 + wm * 64 + i * 16 + (lane >> 4) * 4 + q;
                if (grow < NN) h[(size_t)grow * CC + col] = acc[i][j][q] + bias;
            }
        }
}

// ---------------- propagation: node per 16-lane group, float4/lane, 4-chain ----------------
template <int LAST>
__global__ __launch_bounds__(256) void prop(const float* __restrict__ zin,
                                            const float* __restrict__ h,
                                            float* __restrict__ zout,
                                            const int* __restrict__ rp,
                                            const int2* __restrict__ ed) {
    int node = blockIdx.x * 16 + (threadIdx.x >> 4);
    if (node >= NN) return;
    int l = threadIdx.x & 15;
    int beg = rp[node], end = rp[node + 1];
    f32x4 a0 = {}, a1 = {}, a2 = {}, a3 = {};
    int e = beg;
    for (; e + 3 < end; e += 4) {
        int2 e0 = ed[e], e1 = ed[e + 1], e2 = ed[e + 2], e3 = ed[e + 3];
        a0 += __int_as_float(e0.y) * *(const f32x4*)(zin + (size_t)e0.x * CC + l * 4);
        a1 += __int_as_float(e1.y) * *(const f32x4*)(zin + (size_t)e1.x * CC + l * 4);
        a2 += __int_as_float(e2.y) * *(const f32x4*)(zin + (size_t)e2.x * CC + l * 4);
        a3 += __int_as_float(e3.y) * *(const f32x4*)(zin + (size_t)e3.x * CC + l * 4);
    }
    for (; e < end; ++e) {
        int2 e0 = ed[e];
        a0 += __int_as_float(e0.y) * *(const f32x4*)(zin + (size_t)e0.x * CC + l * 4);
    }
    f32x4 r = 0.9f * ((a0 + a1) + (a2 + a3)) + 0.1f * *(const f32x4*)(h + (size_t)node * CC + l * 4);
    if (!LAST) {
        *(f32x4*)(zout + (size_t)node * CC + l * 4) = r;
    } else {
        // fused log_softmax over the 64 channels (16 lanes x 4)
        float m = fmaxf(fmaxf(r[0], r[1]), fmaxf(r[2], r[3]));
#pragma unroll
        for (int off = 1; off < 16; off <<= 1) m = fmaxf(m, __shfl_xor(m, off));
        float s = expf(r[0] - m) + expf(r[1] - m) + expf(r[2] - m) + expf(r[3] - m);
#pragma unroll
        for (int off = 1; off < 16; off <<= 1) s += __shfl_xor(s, off);
        float ls = m + logf(s);
        f32x4 o;
        o[0] = r[0] - ls; o[1] = r[1] - ls; o[2] = r[2] - ls; o[3] = r[3] - ls;
        *(f32x4*)(zout + (size_t)node * CC + l * 4) = o;
    }
}

extern "C" void kernel_launch(void* const* d_in, const int* in_sizes, int n_in,
                              void* d_out, int out_size, void* d_ws, size_t ws_size,
                              hipStream_t stream) {
    const float* x  = (const float*)d_in[0];
    const float* w0 = (const float*)d_in[1];
    const float* b0 = (const float*)d_in[2];
    const float* w1 = (const float*)d_in[3];
    const float* b1 = (const float*)d_in[4];
    const int*   ei = (const int*)d_in[5];

    char* ws = (char*)d_ws;
    size_t off = 0;
    auto take = [&](size_t n) { size_t r = off; off += (n + 255) & ~(size_t)255; return r; };
    size_t o_h0   = take((size_t)100096 * HH * 2);   // bf16 h0, padded rows; reused as zA
    size_t o_h    = take((size_t)NN * CC * 4);       // f32 h (teleport term)
    size_t o_ed   = take((size_t)(EE + NN) * 8);     // CSR edge data {src, norm}
    size_t o_rp   = take((size_t)(NN + 1) * 4);
    size_t o_cnt  = take((size_t)NN * 4);
    size_t o_fc   = take((size_t)NN * 4);
    size_t o_dinv = take((size_t)NN * 4);
    size_t o_w0t  = take((size_t)HH * FIN * 2);
    size_t o_w1t  = take((size_t)CC * HH * 2);
    size_t o_bs   = take((size_t)SB * 4);
    size_t o_bo   = take((size_t)SB * 4);

    short* h0   = (short*)(ws + o_h0);
    float* h    = (float*)(ws + o_h);
    int2*  ed   = (int2*)(ws + o_ed);
    int*   rp   = (int*)(ws + o_rp);
    int*   cnt  = (int*)(ws + o_cnt);
    int*   fc   = (int*)(ws + o_fc);
    float* dinv = (float*)(ws + o_dinv);
    short* w0t  = (short*)(ws + o_w0t);
    short* w1t  = (short*)(ws + o_w1t);
    int*   bs   = (int*)(ws + o_bs);
    int*   bo   = (int*)(ws + o_bo);
    float* zA   = (float*)(ws + o_h0);   // alias h0 (dead after gemm2)
    float* zB   = (float*)d_out;

    prep_w<<<(FIN * HH + HH * CC + 255) / 256, 256, 0, stream>>>(w0, w1, w0t, w1t);
    hipMemsetAsync(ws + o_cnt, 0, 2 * (((size_t)NN * 4 + 255) & ~(size_t)255), stream);
    hist_kernel<<<(EE + 255) / 256, 256, 0, stream>>>(ei, cnt);
    deg_kernel<<<SB, 256, 0, stream>>>(cnt, dinv, bs);
    scanb_kernel<<<1, 512, 0, stream>>>(bs, bo);
    rp_kernel<<<SB, 256, 0, stream>>>(cnt, bo, rp);
    fill_kernel<<<(EE + NN + 255) / 256, 256, 0, stream>>>(ei, rp, fc, dinv, ed);

    gemm1<<<dim3(782, 2), 256, 0, stream>>>(x, w0t, b0, h0);
    gemm2<<<782, 256, 0, stream>>>(h0, w1t, b1, h);

    const float* in = h;
    for (int k = 0; k < KSTEPS; ++k) {
        float* o = (k & 1) ? zB : zA;
        if (k == KSTEPS - 1)
            prop<1><<<(NN + 15) / 16, 256, 0, stream>>>(in, h, o, rp, ed);
        else
            prop<0><<<(NN + 15) / 16, 256, 0, stream>>>(in, h, o, rp, ed);
        in = o;
    }
}

// Round 3
// 1187.819 us; speedup vs baseline: 2.1517x; 1.3679x over previous
//
#include <hip/hip_runtime.h>
#include <hip/hip_bf16.h>

#define NN 100000
#define EE 3200000
#define FIN 512
#define HH 256
#define CC 64
#define KSTEPS 10
#define SB 391   // ceil(NN/256)

typedef __attribute__((ext_vector_type(8))) short bf16x8;
typedef __attribute__((ext_vector_type(8))) short s16x8;
typedef __attribute__((ext_vector_type(4))) float f32x4;
typedef unsigned short ushort_t;

__device__ __forceinline__ short f2bf(float f) {
    union { __hip_bfloat16 h; short s; } u;
    u.h = __float2bfloat16(f);
    return u.s;
}

// ---------------- weight prep: transpose + bf16 ----------------
__global__ void prep_w(const float* __restrict__ w0, const float* __restrict__ w1,
                       short* __restrict__ w0t, short* __restrict__ w1t) {
    int t = blockIdx.x * blockDim.x + threadIdx.x;
    if (t < FIN * HH) {                   // w0 [512][256] -> w0t [256][512]
        int k = t >> 8, n = t & 255;
        w0t[n * FIN + k] = f2bf(w0[t]);
    } else if (t < FIN * HH + HH * CC) {  // w1 [256][64] -> w1t [64][256]
        int u = t - FIN * HH;
        int k = u >> 6, n = u & 63;
        w1t[n * HH + k] = f2bf(w1[u]);
    }
}

// ---------------- CSR build ----------------
__global__ void hist_kernel(const int* __restrict__ ei, int* __restrict__ cnt) {
    int t = blockIdx.x * blockDim.x + threadIdx.x;
    if (t < EE) {
        unsigned d = (unsigned)ei[EE + t];
        if (d < NN) atomicAdd(&cnt[d], 1);
    }
}

// deg reduce per block + per-node coefficients
__global__ __launch_bounds__(256) void deg_kernel(const int* __restrict__ cnt,
                                                  float* __restrict__ dinv,
                                                  float* __restrict__ wco,
                                                  float* __restrict__ sdg,
                                                  int* __restrict__ bsum) {
    __shared__ int red[256];
    int i = blockIdx.x * 256 + threadIdx.x;
    int d = 0;
    if (i < NN) {
        d = cnt[i] + 1;
        float fd = (float)d;
        dinv[i] = rsqrtf(fd);
        wco[i] = 0.9f / fd;
        sdg[i] = sqrtf(fd);
    }
    red[threadIdx.x] = d;
    __syncthreads();
    for (int off = 128; off > 0; off >>= 1) {
        if (threadIdx.x < off) red[threadIdx.x] += red[threadIdx.x + off];
        __syncthreads();
    }
    if (threadIdx.x == 0) bsum[blockIdx.x] = red[0];
}

// exclusive scan of 391 block sums
__global__ __launch_bounds__(512) void scanb_kernel(const int* __restrict__ bsum,
                                                    int* __restrict__ boff) {
    __shared__ int sh[512];
    int t = threadIdx.x;
    int v = (t < SB) ? bsum[t] : 0;
    sh[t] = v;
    __syncthreads();
    for (int off = 1; off < 512; off <<= 1) {
        int add = (t >= off) ? sh[t - off] : 0;
        __syncthreads();
        sh[t] += add;
        __syncthreads();
    }
    if (t < SB) boff[t] = sh[t] - v;  // exclusive
}

// per-block exclusive scan -> rp
__global__ __launch_bounds__(256) void rp_kernel(const int* __restrict__ cnt,
                                                 const int* __restrict__ boff,
                                                 int* __restrict__ rp) {
    __shared__ int sh[256];
    int i = blockIdx.x * 256 + threadIdx.x;
    int d = (i < NN) ? cnt[i] + 1 : 0;
    sh[threadIdx.x] = d;
    __syncthreads();
    for (int off = 1; off < 256; off <<= 1) {
        int add = (threadIdx.x >= off) ? sh[threadIdx.x - off] : 0;
        __syncthreads();
        sh[threadIdx.x] += add;
        __syncthreads();
    }
    int incl = sh[threadIdx.x];
    if (i < NN) rp[i] = boff[blockIdx.x] + incl - d;
    if (i == NN - 1) rp[NN] = boff[blockIdx.x] + incl;
}

// src-only CSR fill (no per-edge weight needed with pre-scaled v)
__global__ void fill_kernel(const int* __restrict__ ei, const int* __restrict__ rp,
                            int* __restrict__ fc, int* __restrict__ eds) {
    int t = blockIdx.x * blockDim.x + threadIdx.x;
    if (t < EE) {
        unsigned s = (unsigned)ei[t];
        unsigned d = (unsigned)ei[EE + t];
        if (s < NN && d < NN) {
            int pos = rp[d] + atomicAdd(&fc[d], 1);
            eds[pos] = (int)s;
        }
    } else if (t < EE + NN) {
        int i = t - EE;
        eds[rp[i + 1] - 1] = i;   // self loop
    }
}

// ---------------- GEMM1: h0 = relu(x @ w0 + b0), bf16 out [100096][256] ----------------
__global__ __launch_bounds__(256) void gemm1(const float* __restrict__ x,
                                             const short* __restrict__ w0t,
                                             const float* __restrict__ b0,
                                             short* __restrict__ h0) {
    __shared__ __align__(16) short As[128 * 40];
    __shared__ __align__(16) short Bs[256 * 40];
    int tid = threadIdx.x;
    int row0 = blockIdx.x * 128;
    int lane = tid & 63, wid = tid >> 6;
    int wm = wid >> 1, wn = wid & 1;  // wave tile 64 rows x 128 cols
    f32x4 acc[4][8] = {};

    for (int kt = 0; kt < FIN; kt += 32) {
        // stage A: 128 rows x 32 k, fp32 -> bf16
#pragma unroll
        for (int i = 0; i < 4; ++i) {
            int id = i * 256 + tid;
            int r = id >> 3, kg = id & 7;
            int grow = row0 + r;
            float4 v = make_float4(0.f, 0.f, 0.f, 0.f);
            if (grow < NN) v = *(const float4*)(x + (size_t)grow * FIN + kt + kg * 4);
            short4 b;
            b.x = f2bf(v.x); b.y = f2bf(v.y); b.z = f2bf(v.z); b.w = f2bf(v.w);
            *(short4*)(&As[r * 40 + kg * 4]) = b;
        }
        // stage B: 256 cols x 32 k
#pragma unroll
        for (int i = 0; i < 4; ++i) {
            int id = i * 256 + tid;
            int n = id >> 2, kc = id & 3;
            int4 v = *(const int4*)(w0t + (size_t)n * FIN + kt + kc * 8);
            *(int4*)(&Bs[n * 40 + kc * 8]) = v;
        }
        __syncthreads();
        bf16x8 af[4];
#pragma unroll
        for (int i = 0; i < 4; ++i)
            af[i] = *(const bf16x8*)(&As[(wm * 64 + i * 16 + (lane & 15)) * 40 + (lane >> 4) * 8]);
#pragma unroll
        for (int j = 0; j < 8; ++j) {
            bf16x8 bf = *(const bf16x8*)(&Bs[(wn * 128 + j * 16 + (lane & 15)) * 40 + (lane >> 4) * 8]);
#pragma unroll
            for (int i = 0; i < 4; ++i)
                acc[i][j] = __builtin_amdgcn_mfma_f32_16x16x32_bf16(af[i], bf, acc[i][j], 0, 0, 0);
        }
        __syncthreads();
    }
#pragma unroll
    for (int i = 0; i < 4; ++i)
#pragma unroll
        for (int j = 0; j < 8; ++j) {
            int gcol = wn * 128 + j * 16 + (lane & 15);
            float bias = b0[gcol];
#pragma unroll
            for (int q = 0; q < 4; ++q) {
                int grow = row0 + wm * 64 + i * 16 + (lane >> 4) * 4 + q;
                float v = acc[i][j][q] + bias;
                if (v < 0.f) v = 0.f;
                h0[(size_t)grow * HH + gcol] = f2bf(v);
            }
        }
}

// ---------------- GEMM2: h = h0 @ w1 + b1; emits hv = 0.1*dinv*h (f32) and v0 = dinv*h (bf16) ----------------
__global__ __launch_bounds__(256) void gemm2(const short* __restrict__ h0,
                                             const short* __restrict__ w1t,
                                             const float* __restrict__ b1,
                                             const float* __restrict__ dinv,
                                             float* __restrict__ hv,
                                             ushort_t* __restrict__ v0) {
    __shared__ __align__(16) short As[128 * 40];
    __shared__ __align__(16) short Bs[64 * 40];
    int tid = threadIdx.x;
    int row0 = blockIdx.x * 128;
    int lane = tid & 63, wid = tid >> 6;
    int wm = wid >> 1, wn = wid & 1;
    f32x4 acc[4][2] = {};

    for (int kt = 0; kt < HH; kt += 32) {
#pragma unroll
        for (int i = 0; i < 2; ++i) {
            int id = i * 256 + tid;
            int r = id >> 2, kc = id & 3;
            int4 v = *(const int4*)(h0 + (size_t)(row0 + r) * HH + kt + kc * 8);
            *(int4*)(&As[r * 40 + kc * 8]) = v;
        }
        {
            int n = tid >> 2, kc = tid & 3;
            int4 v = *(const int4*)(w1t + (size_t)n * HH + kt + kc * 8);
            *(int4*)(&Bs[n * 40 + kc * 8]) = v;
        }
        __syncthreads();
        bf16x8 af[4], bfr[2];
#pragma unroll
        for (int i = 0; i < 4; ++i)
            af[i] = *(const bf16x8*)(&As[(wm * 64 + i * 16 + (lane & 15)) * 40 + (lane >> 4) * 8]);
#pragma unroll
        for (int j = 0; j < 2; ++j)
            bfr[j] = *(const bf16x8*)(&Bs[(wn * 32 + j * 16 + (lane & 15)) * 40 + (lane >> 4) * 8]);
#pragma unroll
        for (int i = 0; i < 4; ++i)
#pragma unroll
            for (int j = 0; j < 2; ++j)
                acc[i][j] = __builtin_amdgcn_mfma_f32_16x16x32_bf16(af[i], bfr[j], acc[i][j], 0, 0, 0);
        __syncthreads();
    }
#pragma unroll
    for (int i = 0; i < 4; ++i)
#pragma unroll
        for (int j = 0; j < 2; ++j) {
            int col = wn * 32 + j * 16 + (lane & 15);
            float bias = b1[col];
#pragma unroll
            for (int q = 0; q < 4; ++q) {
                int grow = row0 + wm * 64 + i * 16 + (lane >> 4) * 4 + q;
                if (grow < NN) {
                    float hval = acc[i][j][q] + bias;
                    float dv = dinv[grow];
                    hv[(size_t)grow * CC + col] = 0.1f * dv * hval;
                    v0[(size_t)grow * CC + col] = (ushort_t)f2bf(dv * hval);
                }
            }
        }
}

// ---------------- propagation ----------------
__device__ __forceinline__ void gath(float a[8], const ushort_t* __restrict__ vin,
                                     int src, int l) {
    const int4 r = *(const int4*)(vin + ((size_t)src << 6) + (l << 3));
    a[0] += __int_as_float(r.x << 16);
    a[1] += __int_as_float(r.x & 0xffff0000);
    a[2] += __int_as_float(r.y << 16);
    a[3] += __int_as_float(r.y & 0xffff0000);
    a[4] += __int_as_float(r.z << 16);
    a[5] += __int_as_float(r.z & 0xffff0000);
    a[6] += __int_as_float(r.w << 16);
    a[7] += __int_as_float(r.w & 0xffff0000);
}

template <int LAST>
__global__ __launch_bounds__(256) void prop(const ushort_t* __restrict__ vin,
                                            const float* __restrict__ hv,
                                            const float* __restrict__ wco,
                                            const float* __restrict__ sdg,
                                            ushort_t* __restrict__ vout,
                                            float* __restrict__ zout,
                                            const int* __restrict__ rp,
                                            const int* __restrict__ eds) {
    int g = blockIdx.x * 32 + (threadIdx.x >> 3);  // node; grid covers NN exactly
    int l = threadIdx.x & 7;                       // 8 lanes x 8 channels
    int beg = rp[g], end = rp[g + 1];
    float a0[8] = {}, a1[8] = {}, a2[8] = {}, a3[8] = {};
    int e = beg;
    int head = (beg + 3) & ~3;
    if (head > end) head = end;
    for (; e < head; ++e) gath(a0, vin, eds[e], l);
    for (; e + 3 < end; e += 4) {               // e is 4-aligned -> int4 load ok
        int4 ee = *(const int4*)(eds + e);
        gath(a0, vin, ee.x, l);
        gath(a1, vin, ee.y, l);
        gath(a2, vin, ee.z, l);
        gath(a3, vin, ee.w, l);
    }
    for (; e < end; ++e) gath(a1, vin, eds[e], l);

    float w = wco[g];
    f32x4 hv0 = *(const f32x4*)(hv + ((size_t)g << 6) + (l << 3));
    f32x4 hv1 = *(const f32x4*)(hv + ((size_t)g << 6) + (l << 3) + 4);
    float r[8];
#pragma unroll
    for (int c = 0; c < 8; ++c)
        r[c] = w * ((a0[c] + a1[c]) + (a2[c] + a3[c])) + ((c < 4) ? hv0[c] : hv1[c - 4]);
    if (!LAST) {
        s16x8 o;
#pragma unroll
        for (int c = 0; c < 8; ++c) o[c] = f2bf(r[c]);
        *(s16x8*)(vout + ((size_t)g << 6) + (l << 3)) = o;
    } else {
        float sd = sdg[g];
#pragma unroll
        for (int c = 0; c < 8; ++c) r[c] *= sd;
        float m = r[0];
#pragma unroll
        for (int c = 1; c < 8; ++c) m = fmaxf(m, r[c]);
#pragma unroll
        for (int off = 1; off < 8; off <<= 1) m = fmaxf(m, __shfl_xor(m, off));
        float s = 0.f;
#pragma unroll
        for (int c = 0; c < 8; ++c) s += expf(r[c] - m);
#pragma unroll
        for (int off = 1; off < 8; off <<= 1) s += __shfl_xor(s, off);
        float ls = m + logf(s);
        f32x4 o0, o1;
#pragma unroll
        for (int c = 0; c < 4; ++c) { o0[c] = r[c] - ls; o1[c] = r[c + 4] - ls; }
        *(f32x4*)(zout + ((size_t)g << 6) + (l << 3)) = o0;
        *(f32x4*)(zout + ((size_t)g << 6) + (l << 3) + 4) = o1;
    }
}

extern "C" void kernel_launch(void* const* d_in, const int* in_sizes, int n_in,
                              void* d_out, int out_size, void* d_ws, size_t ws_size,
                              hipStream_t stream) {
    const float* x  = (const float*)d_in[0];
    const float* w0 = (const float*)d_in[1];
    const float* b0 = (const float*)d_in[2];
    const float* w1 = (const float*)d_in[3];
    const float* b1 = (const float*)d_in[4];
    const int*   ei = (const int*)d_in[5];

    char* ws = (char*)d_ws;
    size_t off = 0;
    auto take = [&](size_t n) { size_t r = off; off += (n + 255) & ~(size_t)255; return r; };
    size_t o_h0   = take((size_t)100096 * HH * 2);   // bf16 h0; later reused as vB
    size_t o_vA   = take((size_t)NN * CC * 2);       // bf16 v ping buffer
    size_t o_hv   = take((size_t)NN * CC * 4);       // f32 0.1*dinv*h
    size_t o_ed   = take((size_t)(EE + NN) * 4);     // CSR src indices
    size_t o_rp   = take((size_t)(NN + 1) * 4);
    size_t o_cnt  = take((size_t)NN * 4);
    size_t o_fc   = take((size_t)NN * 4);            // must follow o_cnt (joint memset)
    size_t o_dinv = take((size_t)NN * 4);
    size_t o_wco  = take((size_t)NN * 4);
    size_t o_sdg  = take((size_t)NN * 4);
    size_t o_w0t  = take((size_t)HH * FIN * 2);
    size_t o_w1t  = take((size_t)CC * HH * 2);
    size_t o_bs   = take((size_t)SB * 4);
    size_t o_bo   = take((size_t)SB * 4);

    short*    h0   = (short*)(ws + o_h0);
    ushort_t* vA   = (ushort_t*)(ws + o_vA);
    ushort_t* vB   = (ushort_t*)(ws + o_h0);   // alias h0 (dead after gemm2)
    float*    hv   = (float*)(ws + o_hv);
    int*      eds  = (int*)(ws + o_ed);
    int*      rp   = (int*)(ws + o_rp);
    int*      cnt  = (int*)(ws + o_cnt);
    int*      fc   = (int*)(ws + o_fc);
    float*    dinv = (float*)(ws + o_dinv);
    float*    wco  = (float*)(ws + o_wco);
    float*    sdg  = (float*)(ws + o_sdg);
    short*    w0t  = (short*)(ws + o_w0t);
    short*    w1t  = (short*)(ws + o_w1t);
    int*      bs   = (int*)(ws + o_bs);
    int*      bo   = (int*)(ws + o_bo);
    float*    zout = (float*)d_out;

    prep_w<<<(FIN * HH + HH * CC + 255) / 256, 256, 0, stream>>>(w0, w1, w0t, w1t);
    hipMemsetAsync(ws + o_cnt, 0, 2 * (((size_t)NN * 4 + 255) & ~(size_t)255), stream);
    hist_kernel<<<(EE + 255) / 256, 256, 0, stream>>>(ei, cnt);
    deg_kernel<<<SB, 256, 0, stream>>>(cnt, dinv, wco, sdg, bs);
    scanb_kernel<<<1, 512, 0, stream>>>(bs, bo);
    rp_kernel<<<SB, 256, 0, stream>>>(cnt, bo, rp);
    fill_kernel<<<(EE + NN + 255) / 256, 256, 0, stream>>>(ei, rp, fc, eds);

    gemm1<<<782, 256, 0, stream>>>(x, w0t, b0, h0);
    gemm2<<<782, 256, 0, stream>>>(h0, w1t, b1, dinv, hv, vA);

    const ushort_t* in = vA;
    for (int k = 0; k < KSTEPS; ++k) {
        if (k == KSTEPS - 1) {
            prop<1><<<NN / 32, 256, 0, stream>>>(in, hv, wco, sdg, nullptr, zout, rp, eds);
        } else {
            ushort_t* o = (k & 1) ? vA : vB;
            prop<0><<<NN / 32, 256, 0, stream>>>(in, hv, wco, sdg, o, nullptr, rp, eds);
            in = o;
        }
    }
}

// Round 4
// 1060.227 us; speedup vs baseline: 2.4106x; 1.1203x over previous
//
#include <hip/hip_runtime.h>
#include <hip/hip_bf16.h>

#define NN 100000
#define EE 3200000
#define FIN 512
#define HH 256
#define CC 64
#define KSTEPS 10
#define SB 391   // ceil(NN/256)

typedef __attribute__((ext_vector_type(8))) short bf16x8;
typedef __attribute__((ext_vector_type(8))) short s16x8;
typedef __attribute__((ext_vector_type(4))) float f32x4;
typedef unsigned short ushort_t;

__device__ __forceinline__ short f2bf(float f) {
    union { __hip_bfloat16 h; short s; } u;
    u.h = __float2bfloat16(f);
    return u.s;
}

__device__ __forceinline__ void glds16(const void* g, void* l) {
    __builtin_amdgcn_global_load_lds(
        (const __attribute__((address_space(1))) void*)g,
        (__attribute__((address_space(3))) void*)l, 16, 0, 0);
}

// ---------------- weight prep: transpose + bf16 ----------------
__global__ void prep_w(const float* __restrict__ w0, const float* __restrict__ w1,
                       short* __restrict__ w0t, short* __restrict__ w1t) {
    int t = blockIdx.x * blockDim.x + threadIdx.x;
    if (t < FIN * HH) {                   // w0 [512][256] -> w0t [256][512]
        int k = t >> 8, n = t & 255;
        w0t[n * FIN + k] = f2bf(w0[t]);
    } else if (t < FIN * HH + HH * CC) {  // w1 [256][64] -> w1t [64][256]
        int u = t - FIN * HH;
        int k = u >> 6, n = u & 63;
        w1t[n * HH + k] = f2bf(w1[u]);
    }
}

// ---------------- CSR build ----------------
__global__ void hist_kernel(const int* __restrict__ ei, int* __restrict__ cnt) {
    int t = blockIdx.x * blockDim.x + threadIdx.x;
    if (t < EE) {
        unsigned d = (unsigned)ei[EE + t];
        if (d < NN) atomicAdd(&cnt[d], 1);
    }
}

__global__ __launch_bounds__(256) void deg_kernel(const int* __restrict__ cnt,
                                                  float* __restrict__ dinv,
                                                  float* __restrict__ wco,
                                                  float* __restrict__ sdg,
                                                  int* __restrict__ bsum) {
    __shared__ int red[256];
    int i = blockIdx.x * 256 + threadIdx.x;
    int d = 0;
    if (i < NN) {
        d = cnt[i] + 1;
        float fd = (float)d;
        dinv[i] = rsqrtf(fd);
        wco[i] = 0.9f / fd;
        sdg[i] = sqrtf(fd);
    }
    red[threadIdx.x] = d;
    __syncthreads();
    for (int off = 128; off > 0; off >>= 1) {
        if (threadIdx.x < off) red[threadIdx.x] += red[threadIdx.x + off];
        __syncthreads();
    }
    if (threadIdx.x == 0) bsum[blockIdx.x] = red[0];
}

__global__ __launch_bounds__(512) void scanb_kernel(const int* __restrict__ bsum,
                                                    int* __restrict__ boff) {
    __shared__ int sh[512];
    int t = threadIdx.x;
    int v = (t < SB) ? bsum[t] : 0;
    sh[t] = v;
    __syncthreads();
    for (int off = 1; off < 512; off <<= 1) {
        int add = (t >= off) ? sh[t - off] : 0;
        __syncthreads();
        sh[t] += add;
        __syncthreads();
    }
    if (t < SB) boff[t] = sh[t] - v;  // exclusive
}

__global__ __launch_bounds__(256) void rp_kernel(const int* __restrict__ cnt,
                                                 const int* __restrict__ boff,
                                                 int* __restrict__ rp) {
    __shared__ int sh[256];
    int i = blockIdx.x * 256 + threadIdx.x;
    int d = (i < NN) ? cnt[i] + 1 : 0;
    sh[threadIdx.x] = d;
    __syncthreads();
    for (int off = 1; off < 256; off <<= 1) {
        int add = (threadIdx.x >= off) ? sh[threadIdx.x - off] : 0;
        __syncthreads();
        sh[threadIdx.x] += add;
        __syncthreads();
    }
    int incl = sh[threadIdx.x];
    if (i < NN) rp[i] = boff[blockIdx.x] + incl - d;
    if (i == NN - 1) rp[NN] = boff[blockIdx.x] + incl;
}

__global__ void fill_kernel(const int* __restrict__ ei, const int* __restrict__ rp,
                            int* __restrict__ fc, int* __restrict__ eds) {
    int t = blockIdx.x * blockDim.x + threadIdx.x;
    if (t < EE) {
        unsigned s = (unsigned)ei[t];
        unsigned d = (unsigned)ei[EE + t];
        if (s < NN && d < NN) {
            int pos = rp[d] + atomicAdd(&fc[d], 1);
            eds[pos] = (int)s;
        }
    } else if (t < EE + NN) {
        int i = t - EE;
        eds[rp[i + 1] - 1] = i;   // self loop
    }
}

// ---------------- GEMM1: h0 = relu(x @ w0 + b0), bf16 out [100096][256] ----------------
// Tiles: BM=128, BN=128, BK=64. A reg-prefetched (fp32->bf16), B via global_load_lds
// into XOR-swizzled [c][ko^(c&7)] 16B-unit layout, double-buffered.
__global__ __launch_bounds__(256) void gemm1(const float* __restrict__ x,
                                             const short* __restrict__ w0t,
                                             const float* __restrict__ b0,
                                             short* __restrict__ h0) {
    __shared__ __align__(16) short As[128 * 64];
    __shared__ __align__(16) short Bs[2][128 * 64];
    const int tid = threadIdx.x;
    const int lane = tid & 63;
    const int wid = tid >> 6;
    const int wm = wid >> 1, wn = wid & 1;        // 64x64 per wave
    const int bn0 = blockIdx.x * 128;             // 0 or 128
    const long row0 = (long)blockIdx.y * 128;

    const int ar = tid >> 3;                      // 0..31 (+32*i)
    const int ako = tid & 7;                      // k-octet
    const int aslot = ako ^ (ar & 7);             // (i*32+ar)&7 == ar&7
    const int cl = lane >> 3;                     // local col in 8-col group
    const int bko = (lane & 7) ^ cl;              // pre-swizzled global k-octet

    float4 pa[4][2];

    auto loadA = [&](int kt) {
#pragma unroll
        for (int i = 0; i < 4; ++i) {
            long grow = row0 + i * 32 + ar;
            const float* src = x + grow * FIN + kt * 64 + ako * 8;
            if (grow < NN) {
                pa[i][0] = *(const float4*)src;
                pa[i][1] = *(const float4*)(src + 4);
            } else {
                pa[i][0] = make_float4(0.f, 0.f, 0.f, 0.f);
                pa[i][1] = make_float4(0.f, 0.f, 0.f, 0.f);
            }
        }
    };
    auto writeA = [&]() {
#pragma unroll
        for (int i = 0; i < 4; ++i) {
            int r = i * 32 + ar;
            s16x8 o;
            o[0] = f2bf(pa[i][0].x); o[1] = f2bf(pa[i][0].y);
            o[2] = f2bf(pa[i][0].z); o[3] = f2bf(pa[i][0].w);
            o[4] = f2bf(pa[i][1].x); o[5] = f2bf(pa[i][1].y);
            o[6] = f2bf(pa[i][1].z); o[7] = f2bf(pa[i][1].w);
            *(s16x8*)(&As[(r * 8 + aslot) * 8]) = o;
        }
    };
    auto stageB = [&](int kt, int buf) {
#pragma unroll
        for (int j = 0; j < 4; ++j) {
            int blk = wid * 4 + j;                // 8-col group
            const short* g = w0t + (size_t)(bn0 + blk * 8 + cl) * FIN + kt * 64 + bko * 8;
            glds16(g, &Bs[buf][blk * 512]);
        }
    };

    f32x4 acc[4][4] = {};

    stageB(0, 0);
    loadA(0);
    writeA();
    __syncthreads();

    for (int kt = 0; kt < FIN / 64; ++kt) {
        int cur = kt & 1;
        if (kt < FIN / 64 - 1) {
            stageB(kt + 1, cur ^ 1);
            loadA(kt + 1);
        }
#pragma unroll
        for (int ks = 0; ks < 2; ++ks) {
            int ko = ks * 4 + (lane >> 4);
            int slot = ko ^ (lane & 7);
            bf16x8 af[4], bfr[4];
#pragma unroll
            for (int i = 0; i < 4; ++i) {
                int row = wm * 64 + i * 16 + (lane & 15);
                af[i] = *(const bf16x8*)(&As[(row * 8 + slot) * 8]);
            }
#pragma unroll
            for (int j = 0; j < 4; ++j) {
                int col = wn * 64 + j * 16 + (lane & 15);
                bfr[j] = *(const bf16x8*)(&Bs[cur][(col * 8 + slot) * 8]);
            }
#pragma unroll
            for (int i = 0; i < 4; ++i)
#pragma unroll
                for (int j = 0; j < 4; ++j)
                    acc[i][j] = __builtin_amdgcn_mfma_f32_16x16x32_bf16(af[i], bfr[j], acc[i][j], 0, 0, 0);
        }
        __syncthreads();
        if (kt < FIN / 64 - 1) writeA();
        __syncthreads();
    }
#pragma unroll
    for (int j = 0; j < 4; ++j) {
        int gcol = bn0 + wn * 64 + j * 16 + (lane & 15);
        float bias = b0[gcol];
#pragma unroll
        for (int i = 0; i < 4; ++i)
#pragma unroll
            for (int q = 0; q < 4; ++q) {
                long grow = row0 + wm * 64 + i * 16 + (lane >> 4) * 4 + q;
                float v = acc[i][j][q] + bias;
                if (v < 0.f) v = 0.f;
                h0[grow * HH + gcol] = f2bf(v);
            }
    }
}

// ---------------- GEMM2: h = h0 @ w1 + b1; emits hv = 0.1*dinv*h and v0 = dinv*h ----
// Both operands via global_load_lds (bf16), swizzled layout, double-buffered, 1 barrier/iter.
__global__ __launch_bounds__(256) void gemm2(const short* __restrict__ h0,
                                             const short* __restrict__ w1t,
                                             const float* __restrict__ b1,
                                             const float* __restrict__ dinv,
                                             float* __restrict__ hv,
                                             ushort_t* __restrict__ v0) {
    __shared__ __align__(16) short As[2][128 * 64];
    __shared__ __align__(16) short Bs[2][64 * 64];
    const int tid = threadIdx.x;
    const int lane = tid & 63;
    const int wid = tid >> 6;
    const int wm = wid >> 1, wn = wid & 1;        // 64x32 per wave
    const long row0 = (long)blockIdx.x * 128;
    const int rl = lane >> 3;
    const int gko = (lane & 7) ^ rl;

    auto stage = [&](int kt, int buf) {
#pragma unroll
        for (int j = 0; j < 4; ++j) {
            int blk = wid * 4 + j;
            const short* g = h0 + (row0 + blk * 8 + rl) * HH + kt * 64 + gko * 8;
            glds16(g, &As[buf][blk * 512]);
        }
#pragma unroll
        for (int j = 0; j < 2; ++j) {
            int blk = wid * 2 + j;
            const short* g = w1t + (size_t)(blk * 8 + rl) * HH + kt * 64 + gko * 8;
            glds16(g, &Bs[buf][blk * 512]);
        }
    };

    f32x4 acc[4][2] = {};
    stage(0, 0);
    __syncthreads();
    for (int kt = 0; kt < HH / 64; ++kt) {
        int cur = kt & 1;
        if (kt < HH / 64 - 1) stage(kt + 1, cur ^ 1);
#pragma unroll
        for (int ks = 0; ks < 2; ++ks) {
            int ko = ks * 4 + (lane >> 4);
            int slot = ko ^ (lane & 7);
            bf16x8 af[4], bfr[2];
#pragma unroll
            for (int i = 0; i < 4; ++i) {
                int row = wm * 64 + i * 16 + (lane & 15);
                af[i] = *(const bf16x8*)(&As[cur][(row * 8 + slot) * 8]);
            }
#pragma unroll
            for (int j = 0; j < 2; ++j) {
                int col = wn * 32 + j * 16 + (lane & 15);
                bfr[j] = *(const bf16x8*)(&Bs[cur][(col * 8 + slot) * 8]);
            }
#pragma unroll
            for (int i = 0; i < 4; ++i)
#pragma unroll
                for (int j = 0; j < 2; ++j)
                    acc[i][j] = __builtin_amdgcn_mfma_f32_16x16x32_bf16(af[i], bfr[j], acc[i][j], 0, 0, 0);
        }
        __syncthreads();
    }
#pragma unroll
    for (int i = 0; i < 4; ++i)
#pragma unroll
        for (int j = 0; j < 2; ++j) {
            int col = wn * 32 + j * 16 + (lane & 15);
            float bias = b1[col];
#pragma unroll
            for (int q = 0; q < 4; ++q) {
                long grow = row0 + wm * 64 + i * 16 + (lane >> 4) * 4 + q;
                if (grow < NN) {
                    float hval = acc[i][j][q] + bias;
                    float dv = dinv[grow];
                    hv[grow * CC + col] = 0.1f * dv * hval;
                    v0[grow * CC + col] = (ushort_t)f2bf(dv * hval);
                }
            }
        }
}

// ---------------- propagation ----------------
__device__ __forceinline__ void gath(float a[8], const ushort_t* __restrict__ vin,
                                     int src, int l) {
    const int4 r = *(const int4*)(vin + ((size_t)src << 6) + (l << 3));
    a[0] += __int_as_float(r.x << 16);
    a[1] += __int_as_float(r.x & 0xffff0000);
    a[2] += __int_as_float(r.y << 16);
    a[3] += __int_as_float(r.y & 0xffff0000);
    a[4] += __int_as_float(r.z << 16);
    a[5] += __int_as_float(r.z & 0xffff0000);
    a[6] += __int_as_float(r.w << 16);
    a[7] += __int_as_float(r.w & 0xffff0000);
}

template <int LAST>
__global__ __launch_bounds__(256) void prop(const ushort_t* __restrict__ vin,
                                            const float* __restrict__ hv,
                                            const float* __restrict__ wco,
                                            const float* __restrict__ sdg,
                                            ushort_t* __restrict__ vout,
                                            float* __restrict__ zout,
                                            const int* __restrict__ rp,
                                            const int* __restrict__ eds) {
    int g = blockIdx.x * 32 + (threadIdx.x >> 3);
    int l = threadIdx.x & 7;
    int beg = rp[g], end = rp[g + 1];
    float a0[8] = {}, a1[8] = {}, a2[8] = {}, a3[8] = {};
    int e = beg;
    int head = (beg + 3) & ~3;
    if (head > end) head = end;
    for (; e < head; ++e) gath(a0, vin, eds[e], l);
    for (; e + 3 < end; e += 4) {
        int4 ee = *(const int4*)(eds + e);
        gath(a0, vin, ee.x, l);
        gath(a1, vin, ee.y, l);
        gath(a2, vin, ee.z, l);
        gath(a3, vin, ee.w, l);
    }
    for (; e < end; ++e) gath(a1, vin, eds[e], l);

    float w = wco[g];
    f32x4 hv0 = *(const f32x4*)(hv + ((size_t)g << 6) + (l << 3));
    f32x4 hv1 = *(const f32x4*)(hv + ((size_t)g << 6) + (l << 3) + 4);
    float r[8];
#pragma unroll
    for (int c = 0; c < 8; ++c)
        r[c] = w * ((a0[c] + a1[c]) + (a2[c] + a3[c])) + ((c < 4) ? hv0[c] : hv1[c - 4]);
    if (!LAST) {
        s16x8 o;
#pragma unroll
        for (int c = 0; c < 8; ++c) o[c] = f2bf(r[c]);
        *(s16x8*)(vout + ((size_t)g << 6) + (l << 3)) = o;
    } else {
        float sd = sdg[g];
#pragma unroll
        for (int c = 0; c < 8; ++c) r[c] *= sd;
        float m = r[0];
#pragma unroll
        for (int c = 1; c < 8; ++c) m = fmaxf(m, r[c]);
#pragma unroll
        for (int off = 1; off < 8; off <<= 1) m = fmaxf(m, __shfl_xor(m, off));
        float s = 0.f;
#pragma unroll
        for (int c = 0; c < 8; ++c) s += expf(r[c] - m);
#pragma unroll
        for (int off = 1; off < 8; off <<= 1) s += __shfl_xor(s, off);
        float ls = m + logf(s);
        f32x4 o0, o1;
#pragma unroll
        for (int c = 0; c < 4; ++c) { o0[c] = r[c] - ls; o1[c] = r[c + 4] - ls; }
        *(f32x4*)(zout + ((size_t)g << 6) + (l << 3)) = o0;
        *(f32x4*)(zout + ((size_t)g << 6) + (l << 3) + 4) = o1;
    }
}

extern "C" void kernel_launch(void* const* d_in, const int* in_sizes, int n_in,
                              void* d_out, int out_size, void* d_ws, size_t ws_size,
                              hipStream_t stream) {
    const float* x  = (const float*)d_in[0];
    const float* w0 = (const float*)d_in[1];
    const float* b0 = (const float*)d_in[2];
    const float* w1 = (const float*)d_in[3];
    const float* b1 = (const float*)d_in[4];
    const int*   ei = (const int*)d_in[5];

    char* ws = (char*)d_ws;
    size_t off = 0;
    auto take = [&](size_t n) { size_t r = off; off += (n + 255) & ~(size_t)255; return r; };
    size_t o_h0   = take((size_t)100096 * HH * 2);   // bf16 h0; later reused as vB
    size_t o_vA   = take((size_t)NN * CC * 2);       // bf16 v ping buffer
    size_t o_hv   = take((size_t)NN * CC * 4);       // f32 0.1*dinv*h
    size_t o_ed   = take((size_t)(EE + NN) * 4);     // CSR src indices
    size_t o_rp   = take((size_t)(NN + 1) * 4);
    size_t o_cnt  = take((size_t)NN * 4);
    size_t o_fc   = take((size_t)NN * 4);            // must follow o_cnt (joint memset)
    size_t o_dinv = take((size_t)NN * 4);
    size_t o_wco  = take((size_t)NN * 4);
    size_t o_sdg  = take((size_t)NN * 4);
    size_t o_w0t  = take((size_t)HH * FIN * 2);
    size_t o_w1t  = take((size_t)CC * HH * 2);
    size_t o_bs   = take((size_t)SB * 4);
    size_t o_bo   = take((size_t)SB * 4);

    short*    h0   = (short*)(ws + o_h0);
    ushort_t* vA   = (ushort_t*)(ws + o_vA);
    ushort_t* vB   = (ushort_t*)(ws + o_h0);   // alias h0 (dead after gemm2)
    float*    hv   = (float*)(ws + o_hv);
    int*      eds  = (int*)(ws + o_ed);
    int*      rp   = (int*)(ws + o_rp);
    int*      cnt  = (int*)(ws + o_cnt);
    int*      fc   = (int*)(ws + o_fc);
    float*    dinv = (float*)(ws + o_dinv);
    float*    wco  = (float*)(ws + o_wco);
    float*    sdg  = (float*)(ws + o_sdg);
    short*    w0t  = (short*)(ws + o_w0t);
    short*    w1t  = (short*)(ws + o_w1t);
    int*      bs   = (int*)(ws + o_bs);
    int*      bo   = (int*)(ws + o_bo);
    float*    zout = (float*)d_out;

    prep_w<<<(FIN * HH + HH * CC + 255) / 256, 256, 0, stream>>>(w0, w1, w0t, w1t);
    hipMemsetAsync(ws + o_cnt, 0, 2 * (((size_t)NN * 4 + 255) & ~(size_t)255), stream);
    hist_kernel<<<(EE + 255) / 256, 256, 0, stream>>>(ei, cnt);
    deg_kernel<<<SB, 256, 0, stream>>>(cnt, dinv, wco, sdg, bs);
    scanb_kernel<<<1, 512, 0, stream>>>(bs, bo);
    rp_kernel<<<SB, 256, 0, stream>>>(cnt, bo, rp);
    fill_kernel<<<(EE + NN + 255) / 256, 256, 0, stream>>>(ei, rp, fc, eds);

    gemm1<<<dim3(2, 782), 256, 0, stream>>>(x, w0t, b0, h0);
    gemm2<<<782, 256, 0, stream>>>(h0, w1t, b1, dinv, hv, vA);

    const ushort_t* in = vA;
    for (int k = 0; k < KSTEPS; ++k) {
        if (k == KSTEPS - 1) {
            prop<1><<<NN / 32, 256, 0, stream>>>(in, hv, wco, sdg, nullptr, zout, rp, eds);
        } else {
            ushort_t* o = (k & 1) ? vA : vB;
            prop<0><<<NN / 32, 256, 0, stream>>>(in, hv, wco, sdg, o, nullptr, rp, eds);
            in = o;
        }
    }
}

// Round 5
// 928.069 us; speedup vs baseline: 2.7539x; 1.1424x over previous
//
#include <hip/hip_runtime.h>
#include <hip/hip_bf16.h>

#define NN 100000
#define EE 3200000
#define FIN 512
#define HH 256
#define CC 64
#define KSTEPS 10
#define SB 391    // ceil(NN/256)
#define NBUC 782  // ceil(NN/128)
#define EPB 16384 // edges per block in binning kernels
#define NEB 196   // ceil(EE/EPB)

typedef __attribute__((ext_vector_type(8))) short bf16x8;
typedef __attribute__((ext_vector_type(8))) short s16x8;
typedef __attribute__((ext_vector_type(4))) float f32x4;
typedef unsigned short ushort_t;

__device__ __forceinline__ short f2bf(float f) {
    union { __hip_bfloat16 h; short s; } u;
    u.h = __float2bfloat16(f);
    return u.s;
}

__device__ __forceinline__ void glds16(const void* g, void* l) {
    __builtin_amdgcn_global_load_lds(
        (const __attribute__((address_space(1))) void*)g,
        (__attribute__((address_space(3))) void*)l, 16, 0, 0);
}

// ---------------- weight prep: transpose + bf16 ----------------
__global__ void prep_w(const float* __restrict__ w0, const float* __restrict__ w1,
                       short* __restrict__ w0t, short* __restrict__ w1t) {
    int t = blockIdx.x * blockDim.x + threadIdx.x;
    if (t < FIN * HH) {                   // w0 [512][256] -> w0t [256][512]
        int k = t >> 8, n = t & 255;
        w0t[n * FIN + k] = f2bf(w0[t]);
    } else if (t < FIN * HH + HH * CC) {  // w1 [256][64] -> w1t [64][256]
        int u = t - FIN * HH;
        int k = u >> 6, n = u & 63;
        w1t[n * HH + k] = f2bf(w1[u]);
    }
}

// ---------------- binned CSR build ----------------
// 1. count edges per 128-node bucket (LDS hist, block-aggregated)
__global__ __launch_bounds__(256) void bincnt(const int* __restrict__ ei,
                                              int* __restrict__ bcnt) {
    __shared__ int hb[NBUC];
    int tid = threadIdx.x;
    int base = blockIdx.x * EPB;
    for (int i = tid; i < NBUC; i += 256) hb[i] = 0;
    __syncthreads();
#pragma unroll 4
    for (int i = 0; i < EPB / 256; ++i) {
        int t = base + i * 256 + tid;
        if (t < EE) atomicAdd(&hb[(unsigned)ei[EE + t] >> 7], 1);
    }
    __syncthreads();
    for (int i = tid; i < NBUC; i += 256)
        if (hb[i]) atomicAdd(&bcnt[i], hb[i]);
}

// 2. exclusive scan of bucket counts
__global__ __launch_bounds__(1024) void bscan(const int* __restrict__ bcnt,
                                              int* __restrict__ eboff) {
    __shared__ int sh[1024];
    int t = threadIdx.x;
    int v = (t < NBUC) ? bcnt[t] : 0;
    sh[t] = v;
    __syncthreads();
    for (int off = 1; off < 1024; off <<= 1) {
        int add = (t >= off) ? sh[t - off] : 0;
        __syncthreads();
        sh[t] += add;
        __syncthreads();
    }
    if (t < NBUC) eboff[t] = sh[t] - v;
}

// 3. scatter edges into bucket-ordered staging (packed src<<7 | dst&127)
__global__ __launch_bounds__(256) void binfill(const int* __restrict__ ei,
                                               const int* __restrict__ eboff,
                                               int* __restrict__ bfc,
                                               int* __restrict__ stg) {
    __shared__ int hb[NBUC];
    __shared__ int lb[NBUC];
    int tid = threadIdx.x;
    int base = blockIdx.x * EPB;
    for (int i = tid; i < NBUC; i += 256) hb[i] = 0;
    __syncthreads();
#pragma unroll 4
    for (int i = 0; i < EPB / 256; ++i) {
        int t = base + i * 256 + tid;
        if (t < EE) atomicAdd(&hb[(unsigned)ei[EE + t] >> 7], 1);
    }
    __syncthreads();
    for (int i = tid; i < NBUC; i += 256) {
        int c = hb[i];
        lb[i] = eboff[i] + (c ? atomicAdd(&bfc[i], c) : 0);
        hb[i] = 0;
    }
    __syncthreads();
#pragma unroll 4
    for (int i = 0; i < EPB / 256; ++i) {
        int t = base + i * 256 + tid;
        if (t < EE) {
            int s = ei[t];
            int d = ei[EE + t];
            int b = (unsigned)d >> 7;
            int o = atomicAdd(&hb[b], 1);
            stg[lb[b] + o] = (s << 7) | (d & 127);
        }
    }
}

// 4. per-bucket node histogram -> cnt (replaces global-atomic hist)
__global__ __launch_bounds__(256) void bhist(const int* __restrict__ stg,
                                             const int* __restrict__ eboff,
                                             const int* __restrict__ bcnt,
                                             int* __restrict__ cnt) {
    __shared__ int nc[128];
    int b = blockIdx.x, tid = threadIdx.x;
    if (tid < 128) nc[tid] = 0;
    __syncthreads();
    int s0 = eboff[b], n = bcnt[b];
    for (int i = tid; i < n; i += 256) atomicAdd(&nc[stg[s0 + i] & 127], 1);
    __syncthreads();
    int node = b * 128 + tid;
    if (tid < 128 && node < NN) cnt[node] = nc[tid];
}

// per-node coefficients + block degree sums + degree-bin histogram
__global__ __launch_bounds__(256) void deg_kernel(const int* __restrict__ cnt,
                                                  float* __restrict__ dinv,
                                                  float* __restrict__ wco,
                                                  float* __restrict__ sdg,
                                                  int* __restrict__ bsum,
                                                  int* __restrict__ dbc) {
    __shared__ int red[256];
    __shared__ int h[64];
    int tid = threadIdx.x;
    if (tid < 64) h[tid] = 0;
    int i = blockIdx.x * 256 + tid;
    int d = 0, bin = 0;
    if (i < NN) {
        int c = cnt[i];
        d = c + 1;
        bin = min(c, 63);
        float fd = (float)d;
        dinv[i] = rsqrtf(fd);
        wco[i] = 0.9f / fd;
        sdg[i] = sqrtf(fd);
    }
    red[tid] = d;
    __syncthreads();
    if (i < NN) atomicAdd(&h[bin], 1);
    for (int off = 128; off > 0; off >>= 1) {
        if (tid < off) red[tid] += red[tid + off];
        __syncthreads();
    }
    if (tid == 0) bsum[blockIdx.x] = red[0];
    if (tid < 64 && h[tid]) atomicAdd(&dbc[tid], h[tid]);
}

// scan of SB block degree sums + scan of 64 degree bins
__global__ __launch_bounds__(512) void scanb_kernel(const int* __restrict__ bsum,
                                                    int* __restrict__ boff,
                                                    const int* __restrict__ dbc,
                                                    int* __restrict__ dboff) {
    __shared__ int sh[512];
    int t = threadIdx.x;
    int v = (t < SB) ? bsum[t] : 0;
    sh[t] = v;
    __syncthreads();
    for (int off = 1; off < 512; off <<= 1) {
        int add = (t >= off) ? sh[t - off] : 0;
        __syncthreads();
        sh[t] += add;
        __syncthreads();
    }
    if (t < SB) boff[t] = sh[t] - v;  // exclusive
    __syncthreads();
    int v2 = (t < 64) ? dbc[t] : 0;
    __syncthreads();
    if (t < 64) sh[t] = v2;
    __syncthreads();
    for (int off = 1; off < 64; off <<= 1) {
        int add = (t >= off && t < 64) ? sh[t - off] : 0;
        __syncthreads();
        if (t < 64) sh[t] += add;
        __syncthreads();
    }
    if (t < 64) dboff[t] = sh[t] - v2;
}

__global__ __launch_bounds__(256) void rp_kernel(const int* __restrict__ cnt,
                                                 const int* __restrict__ boff,
                                                 int* __restrict__ rp) {
    __shared__ int sh[256];
    int i = blockIdx.x * 256 + threadIdx.x;
    int d = (i < NN) ? cnt[i] + 1 : 0;
    sh[threadIdx.x] = d;
    __syncthreads();
    for (int off = 1; off < 256; off <<= 1) {
        int add = (threadIdx.x >= off) ? sh[threadIdx.x - off] : 0;
        __syncthreads();
        sh[threadIdx.x] += add;
        __syncthreads();
    }
    int incl = sh[threadIdx.x];
    if (i < NN) rp[i] = boff[blockIdx.x] + incl - d;
    if (i == NN - 1) rp[NN] = boff[blockIdx.x] + incl;
}

// 5. per-bucket scatter of final CSR (L2-local region) + self loops
__global__ __launch_bounds__(256) void bfill2(const int* __restrict__ stg,
                                              const int* __restrict__ eboff,
                                              const int* __restrict__ bcnt,
                                              const int* __restrict__ rp,
                                              int* __restrict__ eds) {
    __shared__ int nfc[128];
    __shared__ int rpl[129];
    int b = blockIdx.x, tid = threadIdx.x;
    int nodes = min(128, NN - b * 128);
    if (tid < 128) nfc[tid] = 0;
    if (tid <= 128) rpl[tid] = rp[min(b * 128 + tid, NN)];
    __syncthreads();
    int s0 = eboff[b], n = bcnt[b];
    for (int i = tid; i < n; i += 256) {
        int e = stg[s0 + i];
        int loc = e & 127;
        int o = atomicAdd(&nfc[loc], 1);
        eds[rpl[loc] + o] = e >> 7;
    }
    __syncthreads();
    if (tid < nodes) eds[rpl[tid + 1] - 1] = b * 128 + tid;  // self loop
}

// degree-sorted permutation (counting sort, LDS rank trick)
__global__ __launch_bounds__(256) void dperm(const int* __restrict__ cnt,
                                             const int* __restrict__ dboff,
                                             int* __restrict__ dfc,
                                             int* __restrict__ perm) {
    __shared__ int h[64];
    __shared__ int base[64];
    int tid = threadIdx.x;
    int i = blockIdx.x * 256 + tid;
    if (tid < 64) h[tid] = 0;
    __syncthreads();
    int bin = 0, r = 0;
    bool ok = i < NN;
    if (ok) {
        bin = min(cnt[i], 63);
        r = atomicAdd(&h[bin], 1);
    }
    __syncthreads();
    if (tid < 64) {
        int c = h[tid];
        base[tid] = dboff[tid] + (c ? atomicAdd(&dfc[tid], c) : 0);
    }
    __syncthreads();
    if (ok) perm[base[bin] + r] = i;
}

// ---------------- GEMM1: h0 = relu(x @ w0 + b0), bf16 out [100096][256] ----------------
__global__ __launch_bounds__(256) void gemm1(const float* __restrict__ x,
                                             const short* __restrict__ w0t,
                                             const float* __restrict__ b0,
                                             short* __restrict__ h0) {
    __shared__ __align__(16) short As[128 * 64];
    __shared__ __align__(16) short Bs[2][128 * 64];
    const int tid = threadIdx.x;
    const int lane = tid & 63;
    const int wid = tid >> 6;
    const int wm = wid >> 1, wn = wid & 1;        // 64x64 per wave
    const int bn0 = blockIdx.x * 128;             // 0 or 128
    const long row0 = (long)blockIdx.y * 128;

    const int ar = tid >> 3;                      // 0..31 (+32*i)
    const int ako = tid & 7;                      // k-octet
    const int aslot = ako ^ (ar & 7);
    const int cl = lane >> 3;                     // local col in 8-col group
    const int bko = (lane & 7) ^ cl;              // pre-swizzled global k-octet

    float4 pa[4][2];

    auto loadA = [&](int kt) {
#pragma unroll
        for (int i = 0; i < 4; ++i) {
            long grow = row0 + i * 32 + ar;
            const float* src = x + grow * FIN + kt * 64 + ako * 8;
            if (grow < NN) {
                pa[i][0] = *(const float4*)src;
                pa[i][1] = *(const float4*)(src + 4);
            } else {
                pa[i][0] = make_float4(0.f, 0.f, 0.f, 0.f);
                pa[i][1] = make_float4(0.f, 0.f, 0.f, 0.f);
            }
        }
    };
    auto writeA = [&]() {
#pragma unroll
        for (int i = 0; i < 4; ++i) {
            int r = i * 32 + ar;
            s16x8 o;
            o[0] = f2bf(pa[i][0].x); o[1] = f2bf(pa[i][0].y);
            o[2] = f2bf(pa[i][0].z); o[3] = f2bf(pa[i][0].w);
            o[4] = f2bf(pa[i][1].x); o[5] = f2bf(pa[i][1].y);
            o[6] = f2bf(pa[i][1].z); o[7] = f2bf(pa[i][1].w);
            *(s16x8*)(&As[(r * 8 + aslot) * 8]) = o;
        }
    };
    auto stageB = [&](int kt, int buf) {
#pragma unroll
        for (int j = 0; j < 4; ++j) {
            int blk = wid * 4 + j;
            const short* g = w0t + (size_t)(bn0 + blk * 8 + cl) * FIN + kt * 64 + bko * 8;
            glds16(g, &Bs[buf][blk * 512]);
        }
    };

    f32x4 acc[4][4] = {};

    stageB(0, 0);
    loadA(0);
    writeA();
    __syncthreads();

    for (int kt = 0; kt < FIN / 64; ++kt) {
        int cur = kt & 1;
        if (kt < FIN / 64 - 1) {
            stageB(kt + 1, cur ^ 1);
            loadA(kt + 1);
        }
#pragma unroll
        for (int ks = 0; ks < 2; ++ks) {
            int ko = ks * 4 + (lane >> 4);
            int slot = ko ^ (lane & 7);
            bf16x8 af[4], bfr[4];
#pragma unroll
            for (int i = 0; i < 4; ++i) {
                int row = wm * 64 + i * 16 + (lane & 15);
                af[i] = *(const bf16x8*)(&As[(row * 8 + slot) * 8]);
            }
#pragma unroll
            for (int j = 0; j < 4; ++j) {
                int col = wn * 64 + j * 16 + (lane & 15);
                bfr[j] = *(const bf16x8*)(&Bs[cur][(col * 8 + slot) * 8]);
            }
#pragma unroll
            for (int i = 0; i < 4; ++i)
#pragma unroll
                for (int j = 0; j < 4; ++j)
                    acc[i][j] = __builtin_amdgcn_mfma_f32_16x16x32_bf16(af[i], bfr[j], acc[i][j], 0, 0, 0);
        }
        __syncthreads();
        if (kt < FIN / 64 - 1) writeA();
        __syncthreads();
    }
#pragma unroll
    for (int j = 0; j < 4; ++j) {
        int gcol = bn0 + wn * 64 + j * 16 + (lane & 15);
        float bias = b0[gcol];
#pragma unroll
        for (int i = 0; i < 4; ++i)
#pragma unroll
            for (int q = 0; q < 4; ++q) {
                long grow = row0 + wm * 64 + i * 16 + (lane >> 4) * 4 + q;
                float v = acc[i][j][q] + bias;
                if (v < 0.f) v = 0.f;
                h0[grow * HH + gcol] = f2bf(v);
            }
    }
}

// ---------------- GEMM2: h = h0 @ w1 + b1; emits hv = 0.1*dinv*h and v0 = dinv*h ----
__global__ __launch_bounds__(256) void gemm2(const short* __restrict__ h0,
                                             const short* __restrict__ w1t,
                                             const float* __restrict__ b1,
                                             const float* __restrict__ dinv,
                                             float* __restrict__ hv,
                                             ushort_t* __restrict__ v0) {
    __shared__ __align__(16) short As[2][128 * 64];
    __shared__ __align__(16) short Bs[2][64 * 64];
    const int tid = threadIdx.x;
    const int lane = tid & 63;
    const int wid = tid >> 6;
    const int wm = wid >> 1, wn = wid & 1;
    const long row0 = (long)blockIdx.x * 128;
    const int rl = lane >> 3;
    const int gko = (lane & 7) ^ rl;

    auto stage = [&](int kt, int buf) {
#pragma unroll
        for (int j = 0; j < 4; ++j) {
            int blk = wid * 4 + j;
            const short* g = h0 + (row0 + blk * 8 + rl) * HH + kt * 64 + gko * 8;
            glds16(g, &As[buf][blk * 512]);
        }
#pragma unroll
        for (int j = 0; j < 2; ++j) {
            int blk = wid * 2 + j;
            const short* g = w1t + (size_t)(blk * 8 + rl) * HH + kt * 64 + gko * 8;
            glds16(g, &Bs[buf][blk * 512]);
        }
    };

    f32x4 acc[4][2] = {};
    stage(0, 0);
    __syncthreads();
    for (int kt = 0; kt < HH / 64; ++kt) {
        int cur = kt & 1;
        if (kt < HH / 64 - 1) stage(kt + 1, cur ^ 1);
#pragma unroll
        for (int ks = 0; ks < 2; ++ks) {
            int ko = ks * 4 + (lane >> 4);
            int slot = ko ^ (lane & 7);
            bf16x8 af[4], bfr[2];
#pragma unroll
            for (int i = 0; i < 4; ++i) {
                int row = wm * 64 + i * 16 + (lane & 15);
                af[i] = *(const bf16x8*)(&As[cur][(row * 8 + slot) * 8]);
            }
#pragma unroll
            for (int j = 0; j < 2; ++j) {
                int col = wn * 32 + j * 16 + (lane & 15);
                bfr[j] = *(const bf16x8*)(&Bs[cur][(col * 8 + slot) * 8]);
            }
#pragma unroll
            for (int i = 0; i < 4; ++i)
#pragma unroll
                for (int j = 0; j < 2; ++j)
                    acc[i][j] = __builtin_amdgcn_mfma_f32_16x16x32_bf16(af[i], bfr[j], acc[i][j], 0, 0, 0);
        }
        __syncthreads();
    }
#pragma unroll
    for (int i = 0; i < 4; ++i)
#pragma unroll
        for (int j = 0; j < 2; ++j) {
            int col = wn * 32 + j * 16 + (lane & 15);
            float bias = b1[col];
#pragma unroll
            for (int q = 0; q < 4; ++q) {
                long grow = row0 + wm * 64 + i * 16 + (lane >> 4) * 4 + q;
                if (grow < NN) {
                    float hval = acc[i][j][q] + bias;
                    float dv = dinv[grow];
                    hv[grow * CC + col] = 0.1f * dv * hval;
                    v0[grow * CC + col] = (ushort_t)f2bf(dv * hval);
                }
            }
        }
}

// ---------------- propagation (degree-sorted node order) ----------------
__device__ __forceinline__ void gath(float a[8], const ushort_t* __restrict__ vin,
                                     int src, int l) {
    const int4 r = *(const int4*)(vin + ((size_t)src << 6) + (l << 3));
    a[0] += __int_as_float(r.x << 16);
    a[1] += __int_as_float(r.x & 0xffff0000);
    a[2] += __int_as_float(r.y << 16);
    a[3] += __int_as_float(r.y & 0xffff0000);
    a[4] += __int_as_float(r.z << 16);
    a[5] += __int_as_float(r.z & 0xffff0000);
    a[6] += __int_as_float(r.w << 16);
    a[7] += __int_as_float(r.w & 0xffff0000);
}

template <int LAST>
__global__ __launch_bounds__(256) void prop(const ushort_t* __restrict__ vin,
                                            const float* __restrict__ hv,
                                            const float* __restrict__ wco,
                                            const float* __restrict__ sdg,
                                            ushort_t* __restrict__ vout,
                                            float* __restrict__ zout,
                                            const int* __restrict__ rp,
                                            const int* __restrict__ eds,
                                            const int* __restrict__ perm) {
    int g = perm[blockIdx.x * 32 + (threadIdx.x >> 3)];
    int l = threadIdx.x & 7;
    int beg = rp[g], end = rp[g + 1];
    float a0[8] = {}, a1[8] = {}, a2[8] = {}, a3[8] = {};
    int e = beg;
    int head = (beg + 3) & ~3;
    if (head > end) head = end;
    for (; e < head; ++e) gath(a0, vin, eds[e], l);
    for (; e + 3 < end; e += 4) {
        int4 ee = *(const int4*)(eds + e);
        gath(a0, vin, ee.x, l);
        gath(a1, vin, ee.y, l);
        gath(a2, vin, ee.z, l);
        gath(a3, vin, ee.w, l);
    }
    for (; e < end; ++e) gath(a1, vin, eds[e], l);

    float w = wco[g];
    f32x4 hv0 = *(const f32x4*)(hv + ((size_t)g << 6) + (l << 3));
    f32x4 hv1 = *(const f32x4*)(hv + ((size_t)g << 6) + (l << 3) + 4);
    float r[8];
#pragma unroll
    for (int c = 0; c < 8; ++c)
        r[c] = w * ((a0[c] + a1[c]) + (a2[c] + a3[c])) + ((c < 4) ? hv0[c] : hv1[c - 4]);
    if (!LAST) {
        s16x8 o;
#pragma unroll
        for (int c = 0; c < 8; ++c) o[c] = f2bf(r[c]);
        *(s16x8*)(vout + ((size_t)g << 6) + (l << 3)) = o;
    } else {
        float sd = sdg[g];
#pragma unroll
        for (int c = 0; c < 8; ++c) r[c] *= sd;
        float m = r[0];
#pragma unroll
        for (int c = 1; c < 8; ++c) m = fmaxf(m, r[c]);
#pragma unroll
        for (int off = 1; off < 8; off <<= 1) m = fmaxf(m, __shfl_xor(m, off));
        float s = 0.f;
#pragma unroll
        for (int c = 0; c < 8; ++c) s += expf(r[c] - m);
#pragma unroll
        for (int off = 1; off < 8; off <<= 1) s += __shfl_xor(s, off);
        float ls = m + logf(s);
        f32x4 o0, o1;
#pragma unroll
        for (int c = 0; c < 4; ++c) { o0[c] = r[c] - ls; o1[c] = r[c + 4] - ls; }
        *(f32x4*)(zout + ((size_t)g << 6) + (l << 3)) = o0;
        *(f32x4*)(zout + ((size_t)g << 6) + (l << 3) + 4) = o1;
    }
}

extern "C" void kernel_launch(void* const* d_in, const int* in_sizes, int n_in,
                              void* d_out, int out_size, void* d_ws, size_t ws_size,
                              hipStream_t stream) {
    const float* x  = (const float*)d_in[0];
    const float* w0 = (const float*)d_in[1];
    const float* b0 = (const float*)d_in[2];
    const float* w1 = (const float*)d_in[3];
    const float* b1 = (const float*)d_in[4];
    const int*   ei = (const int*)d_in[5];

    char* ws = (char*)d_ws;
    size_t off = 0;
    auto take = [&](size_t n) { size_t r = off; off += (n + 255) & ~(size_t)255; return r; };
    size_t o_h0    = take((size_t)100096 * HH * 2);   // bf16 h0; later reused as vB
    size_t o_vA    = take((size_t)NN * CC * 2);       // bf16 v ping buffer
    size_t o_hv    = take((size_t)NN * CC * 4);       // f32 0.1*dinv*h; earlier aliased as stg
    size_t o_ed    = take((size_t)(EE + NN) * 4);     // CSR src indices
    size_t o_rp    = take((size_t)(NN + 1) * 4);
    size_t o_cnt   = take((size_t)NN * 4);
    size_t o_dinv  = take((size_t)NN * 4);
    size_t o_wco   = take((size_t)NN * 4);
    size_t o_sdg   = take((size_t)NN * 4);
    size_t o_perm  = take((size_t)NN * 4);
    size_t o_w0t   = take((size_t)HH * FIN * 2);
    size_t o_w1t   = take((size_t)CC * HH * 2);
    size_t o_bs    = take((size_t)SB * 4);
    size_t o_bo    = take((size_t)SB * 4);
    size_t o_eboff = take((size_t)NBUC * 4);
    size_t o_dboff = take((size_t)64 * 4);
    size_t o_z     = take((size_t)(NBUC + NBUC + 64 + 64) * 4);  // bcnt,bfc,dbc,dfc (zeroed)

    short*    h0    = (short*)(ws + o_h0);
    ushort_t* vA    = (ushort_t*)(ws + o_vA);
    ushort_t* vB    = (ushort_t*)(ws + o_h0);   // alias h0 (dead after gemm2)
    float*    hv    = (float*)(ws + o_hv);
    int*      stg   = (int*)(ws + o_hv);        // alias hv (stg dead before gemm2 writes hv)
    int*      eds   = (int*)(ws + o_ed);
    int*      rp    = (int*)(ws + o_rp);
    int*      cnt   = (int*)(ws + o_cnt);
    float*    dinv  = (float*)(ws + o_dinv);
    float*    wco   = (float*)(ws + o_wco);
    float*    sdg   = (float*)(ws + o_sdg);
    int*      perm  = (int*)(ws + o_perm);
    short*    w0t   = (short*)(ws + o_w0t);
    short*    w1t   = (short*)(ws + o_w1t);
    int*      bs    = (int*)(ws + o_bs);
    int*      bo    = (int*)(ws + o_bo);
    int*      eboff = (int*)(ws + o_eboff);
    int*      dboff = (int*)(ws + o_dboff);
    int*      bcnt  = (int*)(ws + o_z);
    int*      bfc   = bcnt + NBUC;
    int*      dbc   = bfc + NBUC;
    int*      dfc   = dbc + 64;
    float*    zout  = (float*)d_out;

    prep_w<<<(FIN * HH + HH * CC + 255) / 256, 256, 0, stream>>>(w0, w1, w0t, w1t);
    hipMemsetAsync(ws + o_z, 0, (size_t)(NBUC + NBUC + 64 + 64) * 4, stream);

    bincnt<<<NEB, 256, 0, stream>>>(ei, bcnt);
    bscan<<<1, 1024, 0, stream>>>(bcnt, eboff);
    binfill<<<NEB, 256, 0, stream>>>(ei, eboff, bfc, stg);
    bhist<<<NBUC, 256, 0, stream>>>(stg, eboff, bcnt, cnt);
    deg_kernel<<<SB, 256, 0, stream>>>(cnt, dinv, wco, sdg, bs, dbc);
    scanb_kernel<<<1, 512, 0, stream>>>(bs, bo, dbc, dboff);
    rp_kernel<<<SB, 256, 0, stream>>>(cnt, bo, rp);
    bfill2<<<NBUC, 256, 0, stream>>>(stg, eboff, bcnt, rp, eds);
    dperm<<<SB, 256, 0, stream>>>(cnt, dboff, dfc, perm);

    gemm1<<<dim3(2, 782), 256, 0, stream>>>(x, w0t, b0, h0);
    gemm2<<<782, 256, 0, stream>>>(h0, w1t, b1, dinv, hv, vA);

    const ushort_t* in = vA;
    for (int k = 0; k < KSTEPS; ++k) {
        if (k == KSTEPS - 1) {
            prop<1><<<NN / 32, 256, 0, stream>>>(in, hv, wco, sdg, nullptr, zout, rp, eds, perm);
        } else {
            ushort_t* o = (k & 1) ? vA : vB;
            prop<0><<<NN / 32, 256, 0, stream>>>(in, hv, wco, sdg, o, nullptr, rp, eds, perm);
            in = o;
        }
    }
}